// Round 5
// baseline (681.688 us; speedup 1.0000x reference)
//
#include <hip/hip_runtime.h>
#include <cstdint>
#include <cstddef>

#define N_NODES 1024
#define K_NEIGH 5
#define L_TIME  2016
#define PATCHSZ 12
#define EMBED   96
#define CINX    6            // (K_NEIGH+1)*IN_CH
#define P_CNT   168          // L_TIME / PATCHSZ
#define KDOT    72           // CINX*PATCHSZ
#define OG_CH   24           // output channels per block (EMBED/4)

// ---------------- Threefry-2x32, JAX partitionable scheme (validated R1) ----
__device__ __forceinline__ uint32_t rotl32(uint32_t x, int r) {
  return (x << r) | (x >> (32 - r));
}

__device__ __forceinline__ uint32_t threefry_bits(uint32_t hi, uint32_t lo) {
  const uint32_t ks0 = 0u;
  const uint32_t ks1 = 42u;
  const uint32_t ks2 = ks0 ^ ks1 ^ 0x1BD11BDAu;
  uint32_t x0 = hi + ks0;
  uint32_t x1 = lo + ks1;
#define TF_ROUND(r) { x0 += x1; x1 = rotl32(x1, (r)); x1 ^= x0; }
  TF_ROUND(13) TF_ROUND(15) TF_ROUND(26) TF_ROUND(6)
  x0 += ks1; x1 += ks2 + 1u;
  TF_ROUND(17) TF_ROUND(29) TF_ROUND(16) TF_ROUND(24)
  x0 += ks2; x1 += ks0 + 2u;
  TF_ROUND(13) TF_ROUND(15) TF_ROUND(26) TF_ROUND(6)
  x0 += ks0; x1 += ks1 + 3u;
  TF_ROUND(17) TF_ROUND(29) TF_ROUND(16) TF_ROUND(24)
  x0 += ks1; x1 += ks2 + 4u;
  TF_ROUND(13) TF_ROUND(15) TF_ROUND(26) TF_ROUND(6)
  x0 += ks2; x1 += ks0 + 5u;
#undef TF_ROUND
  return x0 ^ x1;
}

__device__ __forceinline__ float gumbel_from_bits(uint32_t bits) {
  float f = __uint_as_float((bits >> 9) | 0x3f800000u) - 1.0f;  // [0,1)
  f = fmaxf(f, 1.17549435e-38f);                                // minval=tiny
  return -logf(-logf(f));
}

// ---------------- Kernel 1: Gumbel-max sampling, one block per node --------
// All 5 samples of node n in one pass: log(adj[n][j]) computed ONCE (was 5x),
// 5 k-chains x 4 j-slots per thread = 20 independent ALU chains for ILP.
__global__ __launch_bounds__(256)
void sample_kernel(const float* __restrict__ adj, int* __restrict__ sampled) {
  const int n = blockIdx.x;
  const int tid = threadIdx.x;
  const float* arow = adj + (size_t)n * N_NODES;

  float best[K_NEIGH];
  int   bestj[K_NEIGH];
  #pragma unroll
  for (int k = 0; k < K_NEIGH; ++k) { best[k] = -3.0e38f; bestj[k] = 0; }

  for (int j = tid; j < N_NODES; j += 256) {
    const float la = logf(arow[j]);
    #pragma unroll
    for (int k = 0; k < K_NEIGH; ++k) {
      uint32_t bits = threefry_bits(0u, (uint32_t)((n * K_NEIGH + k) * N_NODES + j));
      float v = la + gumbel_from_bits(bits);
      if (v > best[k]) { best[k] = v; bestj[k] = j; }  // ascending j -> first max
    }
  }

  // wave(64) reduction per k; tie -> lower index (JAX argmax = first max)
  #pragma unroll
  for (int k = 0; k < K_NEIGH; ++k) {
    #pragma unroll
    for (int off = 32; off > 0; off >>= 1) {
      float ov = __shfl_down(best[k], off);
      int   oj = __shfl_down(bestj[k], off);
      if (ov > best[k] || (ov == best[k] && oj < bestj[k])) { best[k] = ov; bestj[k] = oj; }
    }
  }
  __shared__ float sv[4][K_NEIGH];
  __shared__ int   sj[4][K_NEIGH];
  if ((tid & 63) == 0) {
    #pragma unroll
    for (int k = 0; k < K_NEIGH; ++k) { sv[tid >> 6][k] = best[k]; sj[tid >> 6][k] = bestj[k]; }
  }
  __syncthreads();
  if (tid < K_NEIGH) {
    float b = sv[0][tid];
    int  bj = sj[0][tid];
    #pragma unroll
    for (int w = 1; w < 4; ++w) {
      if (sv[w][tid] > b || (sv[w][tid] == b && sj[w][tid] < bj)) { b = sv[w][tid]; bj = sj[w][tid]; }
    }
    sampled[n * K_NEIGH + tid] = bj;
  }
}

// ---------------- Kernel 2: gather + per-patch GEMM, scalar-pipe weights ----
// grid = (B*N, 4) blocks of 64 threads (1 wave). blockIdx.y picks 24 output
// channels -> every weight/bias address is workgroup-uniform (blockIdx + loop
// counters only), pointers __restrict__, no aliasing stores -> compiler can
// emit s_load into SGPRs; even if not, uniform VMEM loads hit L1 (27.6 KB
// weight set fits 32 KB L1; ~9 us aggregate). NO LDS anywhere (R1 showed
// broadcast ds_read_b128 on the per-CU LDS pipe was the 330 us bottleneck).
// x (72 floats/patch) lives in VGPRs, reused for 24 channels.
__global__ __launch_bounds__(64)
void embed_kernel(const float* __restrict__ hist, const float* __restrict__ wgt,
                  const float* __restrict__ bias, const int* __restrict__ sampled,
                  float* __restrict__ out) {
  const int bn = blockIdx.x;          // b*1024 + n
  const int og = blockIdx.y;          // channel group 0..3
  const int n  = bn & (N_NODES - 1);
  const int b  = bn >> 10;
  const int lane = threadIdx.x;       // 0..63

  // 6 source rows: self + 5 sampled neighbors (uniform -> SGPR pointers)
  const float* rows[CINX];
  rows[0] = hist + (size_t)bn * L_TIME;
  #pragma unroll
  for (int k = 0; k < K_NEIGH; ++k) {
    int nb = sampled[n * K_NEIGH + k];
    rows[k + 1] = hist + ((size_t)b * N_NODES + nb) * L_TIME;
  }
  float* outbn = out + (size_t)bn * (EMBED * P_CNT);

  for (int rep = 0; rep < 3; ++rep) {
    const int p = lane + (rep << 6);
    if (p >= P_CNT) break;

    // this patch's 72 inputs -> 18 float4 VGPR loads (48B/lane, coalesced)
    float4 x[18];
    #pragma unroll
    for (int c = 0; c < CINX; ++c) {
      const float4* xp = reinterpret_cast<const float4*>(rows[c] + p * PATCHSZ);
      x[c * 3 + 0] = xp[0];
      x[c * 3 + 1] = xp[1];
      x[c * 3 + 2] = xp[2];
    }

    #pragma unroll 2
    for (int oi = 0; oi < OG_CH; ++oi) {
      const int o = og * OG_CH + oi;                 // uniform
      const float* wp = wgt + o * KDOT;              // uniform, 16B-aligned
      float a0 = 0.f, a1 = 0.f, a2 = 0.f, a3 = 0.f;
      #pragma unroll
      for (int c = 0; c < CINX; ++c) {
        const float4 w0 = *reinterpret_cast<const float4*>(wp + c * PATCHSZ + 0);
        const float4 w1 = *reinterpret_cast<const float4*>(wp + c * PATCHSZ + 4);
        const float4 w2 = *reinterpret_cast<const float4*>(wp + c * PATCHSZ + 8);
        const float4 x0 = x[c * 3 + 0];
        const float4 x1 = x[c * 3 + 1];
        const float4 x2 = x[c * 3 + 2];
        a0 = fmaf(w0.x, x0.x, a0); a1 = fmaf(w0.y, x0.y, a1);
        a2 = fmaf(w0.z, x0.z, a2); a3 = fmaf(w0.w, x0.w, a3);
        a0 = fmaf(w1.x, x1.x, a0); a1 = fmaf(w1.y, x1.y, a1);
        a2 = fmaf(w1.z, x1.z, a2); a3 = fmaf(w1.w, x1.w, a3);
        a0 = fmaf(w2.x, x2.x, a0); a1 = fmaf(w2.y, x2.y, a1);
        a2 = fmaf(w2.z, x2.z, a2); a3 = fmaf(w2.w, x2.w, a3);
      }
      outbn[o * P_CNT + p] = ((a0 + a1) + (a2 + a3)) + bias[o];
    }
  }
}

// ---------------- launch ----------------
extern "C" void kernel_launch(void* const* d_in, const int* in_sizes, int n_in,
                              void* d_out, int out_size, void* d_ws, size_t ws_size,
                              hipStream_t stream) {
  const float* hist = (const float*)d_in[0];  // [4,1024,1,2016]
  const float* adj  = (const float*)d_in[1];  // [1024,1024]
  const float* wgt  = (const float*)d_in[2];  // [96,6,12]
  const float* bias = (const float*)d_in[3];  // [96]
  float* out = (float*)d_out;                 // [4,1024,96,168]
  int* sampled = (int*)d_ws;                  // [1024*5]

  sample_kernel<<<dim3(N_NODES), dim3(256), 0, stream>>>(adj, sampled);
  embed_kernel<<<dim3(4 * N_NODES, 4), dim3(64), 0, stream>>>(hist, wgt, bias, sampled, out);
}

// Round 6
// 576.671 us; speedup vs baseline: 1.1821x; 1.1821x over previous
//
#include <hip/hip_runtime.h>
#include <cstdint>
#include <cstddef>

#define N_NODES 1024
#define K_NEIGH 5
#define L_TIME  2016
#define PATCHSZ 12
#define EMBED   96
#define CINX    6            // (K_NEIGH+1)*IN_CH
#define P_CNT   168          // L_TIME / PATCHSZ
#define KDOT    72           // CINX*PATCHSZ
#define OG_CH   24           // output channels per wave (EMBED/4)

// ---------------- Threefry-2x32, JAX partitionable scheme (validated) ------
__device__ __forceinline__ uint32_t rotl32(uint32_t x, int r) {
  return (x << r) | (x >> (32 - r));
}

__device__ __forceinline__ uint32_t threefry_bits(uint32_t hi, uint32_t lo) {
  const uint32_t ks0 = 0u;
  const uint32_t ks1 = 42u;
  const uint32_t ks2 = ks0 ^ ks1 ^ 0x1BD11BDAu;
  uint32_t x0 = hi + ks0;
  uint32_t x1 = lo + ks1;
#define TF_ROUND(r) { x0 += x1; x1 = rotl32(x1, (r)); x1 ^= x0; }
  TF_ROUND(13) TF_ROUND(15) TF_ROUND(26) TF_ROUND(6)
  x0 += ks1; x1 += ks2 + 1u;
  TF_ROUND(17) TF_ROUND(29) TF_ROUND(16) TF_ROUND(24)
  x0 += ks2; x1 += ks0 + 2u;
  TF_ROUND(13) TF_ROUND(15) TF_ROUND(26) TF_ROUND(6)
  x0 += ks0; x1 += ks1 + 3u;
  TF_ROUND(17) TF_ROUND(29) TF_ROUND(16) TF_ROUND(24)
  x0 += ks1; x1 += ks2 + 4u;
  TF_ROUND(13) TF_ROUND(15) TF_ROUND(26) TF_ROUND(6)
  x0 += ks2; x1 += ks0 + 5u;
#undef TF_ROUND
  return x0 ^ x1;
}

__device__ __forceinline__ float gumbel_from_bits(uint32_t bits) {
  float f = __uint_as_float((bits >> 9) | 0x3f800000u) - 1.0f;  // [0,1)
  f = fmaxf(f, 1.17549435e-38f);                                // minval=tiny
  return -logf(-logf(f));
}

// ---------------- Kernel 1: Gumbel-max sampling, 1024 thr/block ------------
// One j per thread (no stride loop); 5 independent gumbel chains for ILP.
// grid = 1024 nodes. Expected ~10 us total; diagnostic for the ~223 us
// residual seen in R1/R5 (if residual persists -> harness overhead).
__global__ __launch_bounds__(1024)
void sample_kernel(const float* __restrict__ adj, int* __restrict__ sampled) {
  const int n = blockIdx.x;
  const int tid = threadIdx.x;      // == j
  const float la = logf(adj[(size_t)n * N_NODES + tid]);

  float best[K_NEIGH];
  int   bestj[K_NEIGH];
  #pragma unroll
  for (int k = 0; k < K_NEIGH; ++k) {
    uint32_t bits = threefry_bits(0u, (uint32_t)((n * K_NEIGH + k) * N_NODES + tid));
    best[k] = la + gumbel_from_bits(bits);
    bestj[k] = tid;
  }

  // wave(64) reduction per k; tie -> lower index (JAX argmax = first max)
  #pragma unroll
  for (int k = 0; k < K_NEIGH; ++k) {
    #pragma unroll
    for (int off = 32; off > 0; off >>= 1) {
      float ov = __shfl_down(best[k], off);
      int   oj = __shfl_down(bestj[k], off);
      if (ov > best[k] || (ov == best[k] && oj < bestj[k])) { best[k] = ov; bestj[k] = oj; }
    }
  }
  __shared__ float sv[16][K_NEIGH];
  __shared__ int   sj[16][K_NEIGH];
  if ((tid & 63) == 0) {
    #pragma unroll
    for (int k = 0; k < K_NEIGH; ++k) { sv[tid >> 6][k] = best[k]; sj[tid >> 6][k] = bestj[k]; }
  }
  __syncthreads();
  if (tid < K_NEIGH) {
    float b = sv[0][tid];
    int  bj = sj[0][tid];
    #pragma unroll
    for (int w = 1; w < 16; ++w) {
      if (sv[w][tid] > b || (sv[w][tid] == b && sj[w][tid] < bj)) { b = sv[w][tid]; bj = sj[w][tid]; }
    }
    sampled[n * K_NEIGH + tid] = bj;
  }
}

// ---------------- Kernel 2: gather + per-patch GEMM ------------------------
// R1 grid (4096 blocks x 256 thr = 4 waves; single pass over x -> no refetch,
// no 1-wave workgroup-slot cap) + R5 scalar-pipe weights (no LDS, no VMEM
// weight traffic). Wave w owns channels [w*24, w*24+24): the base is forced
// wave-uniform with readfirstlane so the compiler emits merged
// s_load_dwordx16 for the 72 weight floats (SMEM pipe, idle otherwise).
// FMA is v_fma_f32 vdst, sgpr, vgpr, vgpr (1 SGPR operand - legal).
// x (72 floats/patch) per-lane in VGPRs, reused across 24 channels.
__global__ __launch_bounds__(256)
void embed_kernel(const float* __restrict__ hist, const float* __restrict__ wgt,
                  const float* __restrict__ bias, const int* __restrict__ sampled,
                  float* __restrict__ out) {
  const int bn = blockIdx.x;          // b*1024 + n
  const int n  = bn & (N_NODES - 1);
  const int b  = bn >> 10;
  const int tid  = threadIdx.x;
  const int lane = tid & 63;
  // FORCE wave-uniform channel base into an SGPR (tid>>6 is wave-uniform in
  // fact but not provably so to divergence analysis; readfirstlane pins it).
  const int obase = __builtin_amdgcn_readfirstlane((tid >> 6) * OG_CH);

  // 6 source rows: self + 5 sampled neighbors (block-uniform -> SGPR ptrs)
  const float* rows[CINX];
  rows[0] = hist + (size_t)bn * L_TIME;
  #pragma unroll
  for (int k = 0; k < K_NEIGH; ++k) {
    int nb = sampled[n * K_NEIGH + k];
    rows[k + 1] = hist + ((size_t)b * N_NODES + nb) * L_TIME;
  }
  float* outbn = out + (size_t)bn * (EMBED * P_CNT);

  for (int rep = 0; rep < 3; ++rep) {
    const int p = lane + (rep << 6);
    if (p < P_CNT) {
      // this patch's 72 inputs -> 18 float4 VGPR loads (48B/lane, coalesced)
      float4 x[18];
      #pragma unroll
      for (int c = 0; c < CINX; ++c) {
        const float4* xp = reinterpret_cast<const float4*>(rows[c] + p * PATCHSZ);
        x[c * 3 + 0] = xp[0];
        x[c * 3 + 1] = xp[1];
        x[c * 3 + 2] = xp[2];
      }

      for (int oi = 0; oi < OG_CH; ++oi) {
        const int o = obase + oi;                      // wave-uniform
        const float* wp = wgt + (size_t)o * KDOT;      // uniform -> s_load
        float4 w[18];
        #pragma unroll
        for (int q = 0; q < 18; ++q) w[q] = reinterpret_cast<const float4*>(wp)[q];

        float a0 = 0.f, a1 = 0.f, a2 = 0.f, a3 = 0.f;
        #pragma unroll
        for (int c = 0; c < CINX; ++c) {
          const float4 w0 = w[c * 3 + 0];
          const float4 w1 = w[c * 3 + 1];
          const float4 w2 = w[c * 3 + 2];
          const float4 x0 = x[c * 3 + 0];
          const float4 x1 = x[c * 3 + 1];
          const float4 x2 = x[c * 3 + 2];
          a0 = fmaf(w0.x, x0.x, a0); a1 = fmaf(w0.y, x0.y, a1);
          a2 = fmaf(w0.z, x0.z, a2); a3 = fmaf(w0.w, x0.w, a3);
          a0 = fmaf(w1.x, x1.x, a0); a1 = fmaf(w1.y, x1.y, a1);
          a2 = fmaf(w1.z, x1.z, a2); a3 = fmaf(w1.w, x1.w, a3);
          a0 = fmaf(w2.x, x2.x, a0); a1 = fmaf(w2.y, x2.y, a1);
          a2 = fmaf(w2.z, x2.z, a2); a3 = fmaf(w2.w, x2.w, a3);
        }
        outbn[o * P_CNT + p] = ((a0 + a1) + (a2 + a3)) + bias[o];
      }
    }
  }
}

// ---------------- launch ----------------
extern "C" void kernel_launch(void* const* d_in, const int* in_sizes, int n_in,
                              void* d_out, int out_size, void* d_ws, size_t ws_size,
                              hipStream_t stream) {
  const float* hist = (const float*)d_in[0];  // [4,1024,1,2016]
  const float* adj  = (const float*)d_in[1];  // [1024,1024]
  const float* wgt  = (const float*)d_in[2];  // [96,6,12]
  const float* bias = (const float*)d_in[3];  // [96]
  float* out = (float*)d_out;                 // [4,1024,96,168]
  int* sampled = (int*)d_ws;                  // [1024*5]

  sample_kernel<<<dim3(N_NODES), dim3(1024), 0, stream>>>(adj, sampled);
  embed_kernel<<<dim3(4 * N_NODES), dim3(256), 0, stream>>>(hist, wgt, bias, sampled, out);
}

// Round 8
// 421.929 us; speedup vs baseline: 1.6156x; 1.3667x over previous
//
#include <hip/hip_runtime.h>
#include <cstdint>
#include <cstddef>

#define N_NODES 1024
#define K_NEIGH 5
#define L_TIME  2016
#define PATCHSZ 12
#define EMBED   96
#define CINX    6
#define P_CNT   168
#define KDOT    72
#define OUT_PER_BN (EMBED * P_CNT)   // 16128

// d_ws layout (bytes): [0,20480) sampled ints; [24576,+18432) WH frags; then WL
#define WS_WH 24576
#define WS_WL (24576 + 18432)

typedef __attribute__((ext_vector_type(8))) short   bf16x8;   // 8 bf16 = 4 VGPR (guide §3)
typedef __attribute__((ext_vector_type(4))) float   f32x4;
typedef __attribute__((ext_vector_type(4))) unsigned int u32x4;

// ---- bf16 split helpers (RNE) ----
__device__ __forceinline__ uint32_t f2bf_bits(float f) {
  uint32_t u = __float_as_uint(f);
  return (u + 0x7fffu + ((u >> 16) & 1u)) >> 16;
}
__device__ __forceinline__ float bf_hi_f(uint32_t hb) { return __uint_as_float(hb << 16); }

// ---------------- Threefry-2x32, JAX partitionable (validated R1-R6) -------
__device__ __forceinline__ uint32_t rotl32(uint32_t x, int r) {
  return (x << r) | (x >> (32 - r));
}
__device__ __forceinline__ uint32_t threefry_bits(uint32_t hi, uint32_t lo) {
  const uint32_t ks0 = 0u, ks1 = 42u;
  const uint32_t ks2 = ks0 ^ ks1 ^ 0x1BD11BDAu;
  uint32_t x0 = hi + ks0, x1 = lo + ks1;
#define TF_ROUND(r) { x0 += x1; x1 = rotl32(x1, (r)); x1 ^= x0; }
  TF_ROUND(13) TF_ROUND(15) TF_ROUND(26) TF_ROUND(6)
  x0 += ks1; x1 += ks2 + 1u;
  TF_ROUND(17) TF_ROUND(29) TF_ROUND(16) TF_ROUND(24)
  x0 += ks2; x1 += ks0 + 2u;
  TF_ROUND(13) TF_ROUND(15) TF_ROUND(26) TF_ROUND(6)
  x0 += ks0; x1 += ks1 + 3u;
  TF_ROUND(17) TF_ROUND(29) TF_ROUND(16) TF_ROUND(24)
  x0 += ks1; x1 += ks2 + 4u;
  TF_ROUND(13) TF_ROUND(15) TF_ROUND(26) TF_ROUND(6)
  x0 += ks2; x1 += ks0 + 5u;
#undef TF_ROUND
  return x0 ^ x1;
}
__device__ __forceinline__ float gumbel_from_bits(uint32_t bits) {
  float f = __uint_as_float((bits >> 9) | 0x3f800000u) - 1.0f;
  f = fmaxf(f, 1.17549435e-38f);
  return -logf(-logf(f));
}

// ---------------- Kernel 0: pre-pack W into A-frag hi/lo layout ------------
// Frag element (m,kc,L,j): w[o = m*16 + (L&15)][k = kc*32 + (L>>4)*8 + j],
// zero-padded for k>=72. Lane frag = 8 bf16 = 16 B contiguous.
__global__ __launch_bounds__(256)
void wpack_kernel(const float* __restrict__ wgt, char* __restrict__ ws) {
  const int tid = threadIdx.x;
  for (int t = tid; t < 1152; t += 256) {     // 18 (m*3+kc) x 64 lanes
    const int L  = t & 63;
    const int mk = t >> 6;
    const int kc = mk % 3;
    const int m  = mk / 3;
    const int o  = m * 16 + (L & 15);
    const int kbase = kc * 32 + (L >> 4) * 8;
    uint32_t hb[8], lb[8];
    #pragma unroll
    for (int j = 0; j < 8; ++j) {
      const int k = kbase + j;
      float v = (k < KDOT) ? wgt[o * KDOT + k] : 0.0f;
      hb[j] = f2bf_bits(v);
      lb[j] = f2bf_bits(v - bf_hi_f(hb[j]));
    }
    u32x4 ph, pl;
    #pragma unroll
    for (int i = 0; i < 4; ++i) {
      ph[i] = hb[2*i] | (hb[2*i+1] << 16);
      pl[i] = lb[2*i] | (lb[2*i+1] << 16);
    }
    *reinterpret_cast<u32x4*>(ws + WS_WH + mk * 1024 + L * 16) = ph;
    *reinterpret_cast<u32x4*>(ws + WS_WL + mk * 1024 + L * 16) = pl;
  }
}

// ---------------- Kernel 1: Gumbel-max sampling (unchanged R6) -------------
__global__ __launch_bounds__(1024)
void sample_kernel(const float* __restrict__ adj, int* __restrict__ sampled) {
  const int n = blockIdx.x;
  const int tid = threadIdx.x;
  const float la = logf(adj[(size_t)n * N_NODES + tid]);

  float best[K_NEIGH];
  int   bestj[K_NEIGH];
  #pragma unroll
  for (int k = 0; k < K_NEIGH; ++k) {
    uint32_t bits = threefry_bits(0u, (uint32_t)((n * K_NEIGH + k) * N_NODES + tid));
    best[k] = la + gumbel_from_bits(bits);
    bestj[k] = tid;
  }
  #pragma unroll
  for (int k = 0; k < K_NEIGH; ++k) {
    #pragma unroll
    for (int off = 32; off > 0; off >>= 1) {
      float ov = __shfl_down(best[k], off);
      int   oj = __shfl_down(bestj[k], off);
      if (ov > best[k] || (ov == best[k] && oj < bestj[k])) { best[k] = ov; bestj[k] = oj; }
    }
  }
  __shared__ float sv[16][K_NEIGH];
  __shared__ int   sj[16][K_NEIGH];
  if ((tid & 63) == 0) {
    #pragma unroll
    for (int k = 0; k < K_NEIGH; ++k) { sv[tid >> 6][k] = best[k]; sj[tid >> 6][k] = bestj[k]; }
  }
  __syncthreads();
  if (tid < K_NEIGH) {
    float b = sv[0][tid];
    int  bj = sj[0][tid];
    #pragma unroll
    for (int w = 1; w < 16; ++w) {
      if (sv[w][tid] > b || (sv[w][tid] == b && sj[w][tid] < bj)) { b = sv[w][tid]; bj = sj[w][tid]; }
    }
    sampled[n * K_NEIGH + tid] = bj;
  }
}

// ---------------- Kernel 2: persistent MFMA embed --------------------------
// 512 wg x 256 thr (2 wg/CU); each wg loops 8 bn. W-frags (hi+lo, 144 VGPR)
// loaded once per wg from ws. Per bn: stage X hi/lo into LDS in B-frag
// layout (two halves of 6 patch-tiles, 36 KB), then 16x16x32 bf16 MFMA:
// acc = wh*xh + wh*xl + wl*xh (fp32 acc; dropped wl*xl ~2^-18 rel).
// C/D map (m89-verified): col=lane&15 (patch), row=(lane>>4)*4+i (channel).
__global__ __launch_bounds__(256)
void embed_kernel(const float* __restrict__ hist, const char* __restrict__ ws,
                  const float* __restrict__ bias, const int* __restrict__ sampled,
                  float* __restrict__ out) {
  __shared__ __align__(16) char xlds[36864];
  char* XH = xlds;            // 18432 B: [6 tiles][3 kc][16 col][4 kg][16 B]
  char* XL = xlds + 18432;

  const int tid  = threadIdx.x;
  const int L    = tid & 63;
  const int wave = tid >> 6;

  // persistent W-frags: wh/wl[m*3+kc]
  bf16x8 wh[18], wl[18];
  #pragma unroll
  for (int mk = 0; mk < 18; ++mk) {
    wh[mk] = __builtin_bit_cast(bf16x8, *reinterpret_cast<const u32x4*>(ws + WS_WH + mk*1024 + L*16));
    wl[mk] = __builtin_bit_cast(bf16x8, *reinterpret_cast<const u32x4*>(ws + WS_WL + mk*1024 + L*16));
  }
  // bias per lane for the C/D rows this lane owns
  float bv[6][4];
  #pragma unroll
  for (int m = 0; m < 6; ++m)
    #pragma unroll
    for (int i = 0; i < 4; ++i)
      bv[m][i] = bias[m * 16 + (L >> 4) * 4 + i];

  for (int bn = blockIdx.x; bn < 4 * N_NODES; bn += 512) {
    const int n = bn & (N_NODES - 1);
    const int b = bn >> 10;
    const float* rows[CINX];
    rows[0] = hist + (size_t)bn * L_TIME;
    #pragma unroll
    for (int k = 0; k < K_NEIGH; ++k)
      rows[k + 1] = hist + ((size_t)b * N_NODES + sampled[n * K_NEIGH + k]) * L_TIME;
    float* outbn = out + (size_t)bn * OUT_PER_BN;

    for (int h = 0; h < 2; ++h) {
      const int ncols  = h ? 80 : 96;       // h1: patches 96..175 (168.. zero)
      const int ntasks = ncols * 12;        // octets of 8 k per column
      // ---- stage: pack x hi/lo into B-frag layout ----
      for (int t = tid; t < ntasks; t += 256) {
        const int q   = t / ncols;          // k-octet 0..11 (k = 8q..8q+7)
        const int ci  = t - q * ncols;      // column within half
        const int p   = h * 96 + ci;        // global patch
        const int ntl = ci >> 4;
        const int c16 = ci & 15;
        const int kc  = q >> 2;
        const int qg  = q & 3;
        char* dsth = XH + (ntl*3 + kc)*1024 + c16*64 + qg*16;
        char* dstl = XL + (ntl*3 + kc)*1024 + c16*64 + qg*16;
        u32x4 ph = {0,0,0,0}, pl = {0,0,0,0};
        if (q < 9 && p < P_CNT) {           // k<72 and real patch
          const int gk = q * 8;
          const int c0 = gk / 12,       t0 = gk - c0 * 12;        // t0 in {0,8,4}
          const int c1 = (gk + 4) / 12, t1 = (gk + 4) - c1 * 12;  // 16B-aligned
          const float4 f0 = *reinterpret_cast<const float4*>(rows[c0] + p * PATCHSZ + t0);
          const float4 f1 = *reinterpret_cast<const float4*>(rows[c1] + p * PATCHSZ + t1);
          const float v[8] = {f0.x, f0.y, f0.z, f0.w, f1.x, f1.y, f1.z, f1.w};
          uint32_t hb[8], lb[8];
          #pragma unroll
          for (int j = 0; j < 8; ++j) {
            hb[j] = f2bf_bits(v[j]);
            lb[j] = f2bf_bits(v[j] - bf_hi_f(hb[j]));
          }
          #pragma unroll
          for (int i = 0; i < 4; ++i) {
            ph[i] = hb[2*i] | (hb[2*i+1] << 16);
            pl[i] = lb[2*i] | (lb[2*i+1] << 16);
          }
        }
        *reinterpret_cast<u32x4*>(dsth) = ph;
        *reinterpret_cast<u32x4*>(dstl) = pl;
      }
      __syncthreads();
      // ---- compute: waves split the half's patch-tiles ----
      const int T = h ? 5 : 6;
      for (int ntl = wave; ntl < T; ntl += 4) {
        f32x4 acc[6];
        #pragma unroll
        for (int m = 0; m < 6; ++m) acc[m] = {0.f, 0.f, 0.f, 0.f};
        #pragma unroll
        for (int kc = 0; kc < 3; ++kc) {
          const char* sh = XH + (ntl*3 + kc)*1024 + (L & 15)*64 + (L >> 4)*16;
          const char* sl = XL + (ntl*3 + kc)*1024 + (L & 15)*64 + (L >> 4)*16;
          const bf16x8 xh = __builtin_bit_cast(bf16x8, *reinterpret_cast<const u32x4*>(sh));
          const bf16x8 xl = __builtin_bit_cast(bf16x8, *reinterpret_cast<const u32x4*>(sl));
          #pragma unroll
          for (int m = 0; m < 6; ++m) {
            acc[m] = __builtin_amdgcn_mfma_f32_16x16x32_bf16(wh[m*3+kc], xh, acc[m], 0, 0, 0);
            acc[m] = __builtin_amdgcn_mfma_f32_16x16x32_bf16(wh[m*3+kc], xl, acc[m], 0, 0, 0);
            acc[m] = __builtin_amdgcn_mfma_f32_16x16x32_bf16(wl[m*3+kc], xh, acc[m], 0, 0, 0);
          }
        }
        const int p = h * 96 + ntl * 16 + (L & 15);
        if (p < P_CNT) {
          #pragma unroll
          for (int m = 0; m < 6; ++m) {
            const int o = m * 16 + (L >> 4) * 4;
            #pragma unroll
            for (int i = 0; i < 4; ++i)
              outbn[(size_t)(o + i) * P_CNT + p] = acc[m][i] + bv[m][i];
          }
        }
      }
      __syncthreads();
    }
  }
}

// ---------------- launch ----------------
extern "C" void kernel_launch(void* const* d_in, const int* in_sizes, int n_in,
                              void* d_out, int out_size, void* d_ws, size_t ws_size,
                              hipStream_t stream) {
  const float* hist = (const float*)d_in[0];  // [4,1024,1,2016]
  const float* adj  = (const float*)d_in[1];  // [1024,1024]
  const float* wgt  = (const float*)d_in[2];  // [96,6,12]
  const float* bias = (const float*)d_in[3];  // [96]
  float* out = (float*)d_out;                 // [4,1024,96,168]
  char* ws   = (char*)d_ws;                   // sampled @0, W-frags @24576
  int* sampled = (int*)d_ws;

  wpack_kernel<<<dim3(1), dim3(256), 0, stream>>>(wgt, ws);
  sample_kernel<<<dim3(N_NODES), dim3(1024), 0, stream>>>(adj, sampled);
  embed_kernel<<<dim3(512), dim3(256), 0, stream>>>(hist, ws, bias, sampled, out);
}